// Round 13
// baseline (3307.962 us; speedup 1.0000x reference)
//
#include <hip/hip_runtime.h>

typedef __bf16 bf16;
typedef __bf16 bf16x8 __attribute__((ext_vector_type(8)));
typedef float  f32x4  __attribute__((ext_vector_type(4)));

// B=64, S=512, OBS=128, D=512, H=8, F=2048, L=4, A=16; rows M = B*513 = 32832
// R13: THE FIX -- d_out is FLOAT32 (reference output dtype), not bf16.
// R12's probe proved it: bf16 writes land in fp32 low-mantissa bits (invisible);
// zeros gave absmax == max|ref| exactly. Pipeline semantics = shown JAX code
// (verified by R5 on-device recompute + R6 independent naive path).
// Carrier = R8 pipeline verbatim; only final_head output dtype changed.

__global__ __launch_bounds__(256) void cvt_bf16(
    const float* __restrict__ src, bf16* __restrict__ dst, int n)
{
    for (int i = blockIdx.x * 256 + threadIdx.x; i < n; i += gridDim.x * 256)
        dst[i] = (bf16)src[i];
}

__global__ __launch_bounds__(256) void transpose_f32(
    const float* __restrict__ W, bf16* __restrict__ WT, int K, int N, long elemOff)
{
    __shared__ bf16 tile[32][33];
    const int bn = blockIdx.x * 32;
    const int bk = blockIdx.y * 32;
    const int tx = threadIdx.x & 31, ty = threadIdx.x >> 5;
    for (int r = 0; r < 32; r += 8)
        tile[ty + r][tx] = (bf16)W[elemOff + (long)(bk + ty + r) * N + (bn + tx)];
    __syncthreads();
    for (int r = 0; r < 32; r += 8)
        WT[(long)(bn + ty + r) * K + (bk + tx)] = tile[tx][ty + r];
}

__global__ __launch_bounds__(256) void build_x0(
    const float* __restrict__ hs, const int* __restrict__ resets,
    bf16* __restrict__ xb)
{
    const int b = blockIdx.x;
    const bool rz = (resets[b] != 0);
    const long base = (long)b * 513 * 512;
    for (int d = threadIdx.x; d < 512; d += 256)
        xb[base + d] = rz ? (bf16)0.f : (bf16)hs[b * 512 + d];
}

// GEMM: C[M,N] = A[M,K] @ BT[N,K]^T + bias (bf16 in/out, fp32 acc)
// 64x64 tile, BK=32, 4 waves x (2x2) 16x16x32 MFMA. Grids tile M,N exactly.
// ROWMAP==1: out row = m + m/512 + 1. ACT: 0 none, 1 relu, 2 relu+1e-3.
template<int ROWMAP, int ACT>
__global__ __launch_bounds__(256) void gemm_bf16(
    const bf16* __restrict__ A, const bf16* __restrict__ BT,
    const bf16* __restrict__ bias, bf16* __restrict__ outB,
    int M, int N, int K)
{
    __shared__ bf16 As[64][40];
    __shared__ bf16 Bs[64][40];
    const int tid  = threadIdx.x;
    const int wave = tid >> 6;
    const int lane = tid & 63;
    const int q    = lane >> 4;
    const int lm   = lane & 15;
    const int wr   = wave >> 1, wc = wave & 1;
    const int m0   = blockIdx.y * 64, n0 = blockIdx.x * 64;
    const int lrow = tid >> 2;
    const int lk8  = (tid & 3) * 8;

    const f32x4 vzero = {0.f, 0.f, 0.f, 0.f};
    f32x4 acc[2][2];
    for (int i = 0; i < 2; i++) for (int j = 0; j < 2; j++) acc[i][j] = vzero;

    const bf16* Ab = A  + (long)(m0 + lrow) * K + lk8;
    const bf16* Bb = BT + (long)(n0 + lrow) * K + lk8;

    for (int k0 = 0; k0 < K; k0 += 32) {
        *(uint4*)(&As[lrow][lk8]) = *(const uint4*)(Ab + k0);
        *(uint4*)(&Bs[lrow][lk8]) = *(const uint4*)(Bb + k0);
        __syncthreads();
        bf16x8 a0 = *(const bf16x8*)(&As[wr * 32 + lm][q * 8]);
        bf16x8 a1 = *(const bf16x8*)(&As[wr * 32 + 16 + lm][q * 8]);
        bf16x8 b0 = *(const bf16x8*)(&Bs[wc * 32 + lm][q * 8]);
        bf16x8 b1 = *(const bf16x8*)(&Bs[wc * 32 + 16 + lm][q * 8]);
        acc[0][0] = __builtin_amdgcn_mfma_f32_16x16x32_bf16(a0, b0, acc[0][0], 0, 0, 0);
        acc[0][1] = __builtin_amdgcn_mfma_f32_16x16x32_bf16(a0, b1, acc[0][1], 0, 0, 0);
        acc[1][0] = __builtin_amdgcn_mfma_f32_16x16x32_bf16(a1, b0, acc[1][0], 0, 0, 0);
        acc[1][1] = __builtin_amdgcn_mfma_f32_16x16x32_bf16(a1, b1, acc[1][1], 0, 0, 0);
        __syncthreads();
    }

    // C/D layout: col = lane&15, row = (lane>>4)*4 + r   [verified m89/m91 + R5]
    for (int i = 0; i < 2; i++) for (int j = 0; j < 2; j++) {
        const int col = n0 + wc * 32 + j * 16 + lm;
        const float bv = (float)bias[col];
        for (int r = 0; r < 4; r++) {
            int row = m0 + wr * 32 + i * 16 + q * 4 + r;
            float vv = acc[i][j][r] + bv;
            if (ACT >= 1) vv = fmaxf(vv, 0.f);
            if (ACT == 2) vv += 1e-3f;
            if (ROWMAP == 1) row = row + (row >> 9) + 1;
            outB[(long)row * N + col] = (bf16)vv;
        }
    }
}

// FAVOR+ attention, one block per (b,h). Layouts (B,513,H,64).
// attn_out ALIASES pq (tile staged to LDS + barrier before overwrite).
__global__ __launch_bounds__(256) void favor_attn(
    const bf16* pq, const bf16* __restrict__ pk,
    const bf16* __restrict__ v,  bf16* attn_out)
{
    const int b = blockIdx.x >> 3, h = blockIdx.x & 7;
    __shared__ float kvS[64][65];
    __shared__ float ksumS[64];
    __shared__ float pkS[64][64];
    __shared__ float vS[64][64];
    const int t = threadIdx.x;
    const long bh_base = ((long)b * 513) * 8 + h;

    float acc[16] = {};
    float ks = 0.f;
    const int d  = t & 63;
    const int mg = (t >> 6) * 16;

    for (int s0 = 0; s0 < 513; s0 += 64) {
        const int cs = min(64, 513 - s0);
        for (int idx = t; idx < cs * 64; idx += 256) {
            int s = idx >> 6, m = idx & 63;
            long g = (bh_base + (long)(s0 + s) * 8) * 64 + m;
            pkS[s][m] = (float)pk[g];
            vS[s][m]  = (float)v[g];
        }
        __syncthreads();
        for (int s = 0; s < cs; s++) {
            float vv = vS[s][d];
            #pragma unroll
            for (int i = 0; i < 16; i++) acc[i] += pkS[s][mg + i] * vv;
        }
        if (t < 64) { for (int s = 0; s < cs; s++) ks += pkS[s][t]; }
        __syncthreads();
    }
    for (int i = 0; i < 16; i++) kvS[mg + i][d] = acc[i];
    if (t < 64) ksumS[t] = ks;
    __syncthreads();

    const int sg = t >> 6;
    for (int s0 = 0; s0 < 513; s0 += 64) {
        const int cs = min(64, 513 - s0);
        for (int idx = t; idx < cs * 64; idx += 256) {
            int s = idx >> 6, m = idx & 63;
            pkS[s][m] = (float)pq[(bh_base + (long)(s0 + s) * 8) * 64 + m];
        }
        __syncthreads();
        for (int s = sg; s < cs; s += 4) {
            float num = 0.f, den = 0.f;
            #pragma unroll 8
            for (int m = 0; m < 64; m++) {
                float p = pkS[s][m];
                num += p * kvS[m][d];
                den += p * ksumS[m];
            }
            attn_out[(bh_base + (long)(s0 + s) * 8) * 64 + d] = (bf16)(num / den);
        }
        __syncthreads();
    }
}

// xb = LN(y + xb) * s + b  (bf16 in/out, fp32 math, fp32 params). wave/row.
__global__ __launch_bounds__(256) void ln_res(
    const bf16* __restrict__ y, const float* __restrict__ sc,
    const float* __restrict__ bi, bf16* __restrict__ xb)
{
    const int row  = blockIdx.x * 4 + (threadIdx.x >> 6);
    const int lane = threadIdx.x & 63;
    const bf16* yr = y  + (long)row * 512 + lane * 8;
    bf16*       xr = xb + (long)row * 512 + lane * 8;
    bf16x8 yv = *(const bf16x8*)yr;
    bf16x8 xv = *(const bf16x8*)xr;
    float v[8];
    float sum = 0.f;
    #pragma unroll
    for (int i = 0; i < 8; i++) { v[i] = (float)yv[i] + (float)xv[i]; sum += v[i]; }
    #pragma unroll
    for (int o = 32; o; o >>= 1) sum += __shfl_xor(sum, o);
    const float mean = sum * (1.f / 512.f);
    float vs = 0.f;
    #pragma unroll
    for (int i = 0; i < 8; i++) { float dd = v[i] - mean; vs += dd * dd; }
    #pragma unroll
    for (int o = 32; o; o >>= 1) vs += __shfl_xor(vs, o);
    const float rstd = rsqrtf(vs * (1.f / 512.f) + 1e-6f);
    bf16x8 ov;
    #pragma unroll
    for (int i = 0; i < 8; i++)
        ov[i] = (bf16)((v[i] - mean) * rstd * sc[lane * 8 + i] + bi[lane * 8 + i]);
    *(bf16x8*)xr = ov;
}

// FP32 OUTPUT: out[0:32768] = x[:,0,:] (fp32); out[32768:] = x[:,0,:]@Wqp + bqp
__global__ __launch_bounds__(256) void final_head(
    const bf16* __restrict__ xb, const float* __restrict__ Wqp,
    const float* __restrict__ bqp, float* __restrict__ out)
{
    const int b = blockIdx.x;
    const bf16* xr = xb + (long)b * 513 * 512;
    for (int i = threadIdx.x; i < 512; i += 256) out[b * 512 + i] = (float)xr[i];
    const int a = threadIdx.x & 15, g = threadIdx.x >> 4;   // 16 k-groups of 32
    float p = 0.f;
    for (int k = g * 32; k < g * 32 + 32; k++)
        p += (float)xr[k] * Wqp[k * 16 + a];
    __shared__ float red[256];
    red[threadIdx.x] = p;
    __syncthreads();
    if (threadIdx.x < 16) {
        float s = bqp[a];
        for (int g2 = 0; g2 < 16; g2++) s += red[g2 * 16 + a];
        out[64 * 512 + b * 16 + a] = s;
    }
}

extern "C" void kernel_launch(void* const* d_in, const int* in_sizes, int n_in,
                              void* d_out, int out_size, void* d_ws, size_t ws_size,
                              hipStream_t stream)
{
    (void)in_sizes; (void)n_in; (void)out_size; (void)ws_size;
    const float* hs    = (const float*)d_in[0];
    const float* ins   = (const float*)d_in[1];
    const int*   resets= (const int*)d_in[2];
    const float* W_emb = (const float*)d_in[3];
    const float* b_emb = (const float*)d_in[4];
    const float* Wq    = (const float*)d_in[5];
    const float* bq    = (const float*)d_in[6];
    const float* Wk    = (const float*)d_in[7];
    const float* bk    = (const float*)d_in[8];
    const float* Wv    = (const float*)d_in[9];
    const float* bv    = (const float*)d_in[10];
    const float* Wo    = (const float*)d_in[11];
    const float* bo    = (const float*)d_in[12];
    const float* ln1s  = (const float*)d_in[13];
    const float* ln1b  = (const float*)d_in[14];
    const float* ln2s  = (const float*)d_in[15];
    const float* ln2b  = (const float*)d_in[16];
    const float* W1    = (const float*)d_in[17];
    const float* b1    = (const float*)d_in[18];
    const float* W2    = (const float*)d_in[19];
    const float* b2    = (const float*)d_in[20];
    const float* Wqp   = (const float*)d_in[21];
    const float* bqp   = (const float*)d_in[22];
    float* out = (float*)d_out;   // *** FP32 OUTPUT (reference dtype) ***
    char* ws  = (char*)d_ws;

    // ---- workspace layout (bytes), peak ~149.8 MB (proven safe R2-R9) ----
    bf16* xb = (bf16*)(ws);                         // 33,619,968
    bf16* f  = (bf16*)(ws + 33619968);              // 67,371,008 (16448 x 2048)
    bf16* pq = f;                                   // alias
    bf16* pk = (bf16*)(ws + 67239936);              // pq + 33,619,968
    bf16* vv = (bf16*)(ws + 100990976);             // 33,619,968 (y aliases)
    bf16* ao = pq;
    bf16* y  = vv;
    bf16* WembT = (bf16*)(ws + 134610944);          // 131,072
    char* LW    = ws + 134742016;                   // 6,291,456 (per-layer WT)
    bf16* insb  = (bf16*)(ws + 141033472);          // 8,388,608
    bf16* sp    = (bf16*)(ws + 149422080);          // bias scratch (bf16)
    bf16* b_embb = sp + 0;
    bf16* bqb    = sp + 512;
    bf16* bkb    = sp + 2560;
    bf16* bvb    = sp + 4608;
    bf16* bob    = sp + 6656;
    bf16* b1b    = sp + 8704;
    bf16* b2b    = sp + 16896;

    const bf16* WqT = (const bf16*)(LW + 0);
    const bf16* WkT = (const bf16*)(LW + 524288);
    const bf16* WvT = (const bf16*)(LW + 1048576);
    const bf16* WoT = (const bf16*)(LW + 1572864);
    const bf16* W1T = (const bf16*)(LW + 2097152);
    const bf16* W2T = (const bf16*)(LW + 4194304);

    cvt_bf16<<<4096, 256, 0, stream>>>(ins,  insb,   4194304);
    cvt_bf16<<<2,    256, 0, stream>>>(b_emb, b_embb, 512);
    cvt_bf16<<<8,    256, 0, stream>>>(bq,   bqb,    2048);
    cvt_bf16<<<8,    256, 0, stream>>>(bk,   bkb,    2048);
    cvt_bf16<<<8,    256, 0, stream>>>(bv,   bvb,    2048);
    cvt_bf16<<<8,    256, 0, stream>>>(bo,   bob,    2048);
    cvt_bf16<<<32,   256, 0, stream>>>(b1,   b1b,    8192);
    cvt_bf16<<<8,    256, 0, stream>>>(b2,   b2b,    2048);

    transpose_f32<<<dim3(16, 4), 256, 0, stream>>>(W_emb, WembT, 128, 512, 0);
    build_x0<<<64, 256, 0, stream>>>(hs, resets, xb);
    gemm_bf16<1, 0><<<dim3(8, 512), 256, 0, stream>>>(
        insb, WembT, b_embb, xb, 32768, 512, 128);

    for (int l = 0; l < 4; l++) {
        const long o512  = (long)l * 262144;
        const long o2048 = (long)l * 1048576;
        transpose_f32<<<dim3(16, 16), 256, 0, stream>>>(Wq, (bf16*)(LW + 0),       512, 512,  o512);
        transpose_f32<<<dim3(16, 16), 256, 0, stream>>>(Wk, (bf16*)(LW + 524288),  512, 512,  o512);
        transpose_f32<<<dim3(16, 16), 256, 0, stream>>>(Wv, (bf16*)(LW + 1048576), 512, 512,  o512);
        transpose_f32<<<dim3(16, 16), 256, 0, stream>>>(Wo, (bf16*)(LW + 1572864), 512, 512,  o512);
        transpose_f32<<<dim3(64, 16), 256, 0, stream>>>(W1, (bf16*)(LW + 2097152), 512, 2048, o2048);
        transpose_f32<<<dim3(16, 64), 256, 0, stream>>>(W2, (bf16*)(LW + 4194304), 2048, 512, o2048);

        gemm_bf16<0, 2><<<dim3(8, 513), 256, 0, stream>>>(
            xb, WqT, bqb + l * 512, pq, 32832, 512, 512);
        gemm_bf16<0, 2><<<dim3(8, 513), 256, 0, stream>>>(
            xb, WkT, bkb + l * 512, pk, 32832, 512, 512);
        gemm_bf16<0, 0><<<dim3(8, 513), 256, 0, stream>>>(
            xb, WvT, bvb + l * 512, vv, 32832, 512, 512);
        favor_attn<<<512, 256, 0, stream>>>(pq, pk, vv, ao);
        gemm_bf16<0, 0><<<dim3(8, 513), 256, 0, stream>>>(
            ao, WoT, bob + l * 512, y, 32832, 512, 512);
        ln_res<<<8208, 256, 0, stream>>>(y, ln1s + l * 512, ln1b + l * 512, xb);
        const int r0s[2] = {0, 16384};
        const int mcs[2] = {16384, 16448};
        for (int c = 0; c < 2; c++) {
            gemm_bf16<0, 1><<<dim3(32, mcs[c] / 64), 256, 0, stream>>>(
                xb + (long)r0s[c] * 512, W1T, b1b + l * 2048, f, mcs[c], 2048, 512);
            gemm_bf16<0, 0><<<dim3(8, mcs[c] / 64), 256, 0, stream>>>(
                f, W2T, b2b + l * 512, y + (long)r0s[c] * 512, mcs[c], 512, 2048);
        }
        ln_res<<<8208, 256, 0, stream>>>(y, ln2s + l * 512, ln2b + l * 512, xb);
    }

    final_head<<<64, 256, 0, stream>>>(xb, Wqp, bqp, out);
}

// Round 14
// 2137.767 us; speedup vs baseline: 1.5474x; 1.5474x over previous
//
#include <hip/hip_runtime.h>

typedef __bf16 bf16;
typedef __bf16 bf16x8 __attribute__((ext_vector_type(8)));
typedef float  f32x4  __attribute__((ext_vector_type(4)));

// B=64, S=512, OBS=128, D=512, H=8, F=2048, L=4, A=16; rows M = B*513 = 32832
// R14: 128x128-tile MFMA GEMM (ladder step m93) + full-MFMA FAVOR attention.
// Output fp32 (R13 fix). ws peak ~149.4 MB.

__global__ __launch_bounds__(256) void cvt_bf16(
    const float* __restrict__ src, bf16* __restrict__ dst, int n)
{
    for (int i = blockIdx.x * 256 + threadIdx.x; i < n; i += gridDim.x * 256)
        dst[i] = (bf16)src[i];
}

__global__ __launch_bounds__(256) void transpose_f32(
    const float* __restrict__ W, bf16* __restrict__ WT, int K, int N, long elemOff)
{
    __shared__ bf16 tile[32][33];
    const int bn = blockIdx.x * 32;
    const int bk = blockIdx.y * 32;
    const int tx = threadIdx.x & 31, ty = threadIdx.x >> 5;
    for (int r = 0; r < 32; r += 8)
        tile[ty + r][tx] = (bf16)W[elemOff + (long)(bk + ty + r) * N + (bn + tx)];
    __syncthreads();
    for (int r = 0; r < 32; r += 8)
        WT[(long)(bn + ty + r) * K + (bk + tx)] = tile[tx][ty + r];
}

__global__ __launch_bounds__(256) void build_x0(
    const float* __restrict__ hs, const int* __restrict__ resets,
    bf16* __restrict__ xb)
{
    const int b = blockIdx.x;
    const bool rz = (resets[b] != 0);
    const long base = (long)b * 513 * 512;
    for (int d = threadIdx.x; d < 512; d += 256)
        xb[base + d] = rz ? (bf16)0.f : (bf16)hs[b * 512 + d];
}

// GEMM: C[M,N] = A[M,K] @ BT[N,K]^T + bias(fp32).  128x128 tile, BK=32,
// 4 waves x (4x4) 16x16x32 MFMA tiles.  N % 128 == 0; M handled by overlap
// clamp (duplicate tiles write identical values -- benign).
// ROWMAP==1: out row = m + m/512 + 1. ACT: 0 none, 1 relu, 2 relu+1e-3.
template<int ROWMAP, int ACT>
__global__ __launch_bounds__(256) void gemm128(
    const bf16* __restrict__ A, const bf16* __restrict__ BT,
    const float* __restrict__ bias, bf16* __restrict__ outB,
    int M, int N, int K)
{
    __shared__ bf16 As[128][40];
    __shared__ bf16 Bs[128][40];
    const int tid  = threadIdx.x;
    const int wave = tid >> 6;
    const int lane = tid & 63;
    const int q    = lane >> 4;
    const int lm   = lane & 15;
    const int wr   = wave >> 1, wc = wave & 1;
    int m0 = blockIdx.y * 128;
    if (m0 > M - 128) m0 = M - 128;            // tail overlap clamp
    const int n0 = blockIdx.x * 128;
    const int srow = tid >> 1;                 // 0..127
    const int se   = (tid & 1) * 16;           // elem offset 0/16

    f32x4 acc[4][4];
    for (int i = 0; i < 4; i++) for (int j = 0; j < 4; j++)
        for (int r = 0; r < 4; r++) acc[i][j][r] = 0.f;

    const bf16* Ab = A  + (long)(m0 + srow) * K + se;
    const bf16* Bb = BT + (long)(n0 + srow) * K + se;

    for (int k0 = 0; k0 < K; k0 += 32) {
        uint4 a0 = *(const uint4*)(Ab + k0);
        uint4 a1 = *(const uint4*)(Ab + k0 + 8);
        uint4 b0 = *(const uint4*)(Bb + k0);
        uint4 b1 = *(const uint4*)(Bb + k0 + 8);
        __syncthreads();                       // prior-iter frag reads done
        *(uint4*)(&As[srow][se])     = a0;
        *(uint4*)(&As[srow][se + 8]) = a1;
        *(uint4*)(&Bs[srow][se])     = b0;
        *(uint4*)(&Bs[srow][se + 8]) = b1;
        __syncthreads();
        bf16x8 af[4], bf[4];
        #pragma unroll
        for (int i = 0; i < 4; i++)
            af[i] = *(const bf16x8*)(&As[wr * 64 + i * 16 + lm][q * 8]);
        #pragma unroll
        for (int j = 0; j < 4; j++)
            bf[j] = *(const bf16x8*)(&Bs[wc * 64 + j * 16 + lm][q * 8]);
        #pragma unroll
        for (int i = 0; i < 4; i++)
            #pragma unroll
            for (int j = 0; j < 4; j++)
                acc[i][j] = __builtin_amdgcn_mfma_f32_16x16x32_bf16(
                    af[i], bf[j], acc[i][j], 0, 0, 0);
    }

    // C/D: col = lane&15, row = (lane>>4)*4 + r  [session-verified]
    #pragma unroll
    for (int j = 0; j < 4; j++) {
        const int col = n0 + wc * 64 + j * 16 + lm;
        const float bv = bias[col];
        #pragma unroll
        for (int i = 0; i < 4; i++) {
            #pragma unroll
            for (int r = 0; r < 4; r++) {
                int row = m0 + wr * 64 + i * 16 + q * 4 + r;
                float vv = acc[i][j][r] + bv;
                if (ACT >= 1) vv = fmaxf(vv, 0.f);
                if (ACT == 2) vv += 1e-3f;
                if (ROWMAP == 1) row = row + (row >> 9) + 1;
                outB[(long)row * N + col] = (bf16)vv;
            }
        }
    }
}

// FAVOR+ attention, full MFMA.  One block per (b,h), 4 waves.
// Phase A: kv[m][d] = sum_s pk[s][m] v[s][d]  (A=pkT[m][s], B=vT[d][s])
// Phase B: num[s][d] = sum_m pq[s][m] kv[m][d] (A=pqS[s][m], B=kvT[d][m])
// ksum via staging-time register partials + LDS atomics; den via VALU dot.
// ao may alias pq (each tile staged to LDS + barrier before overwrite).
#define FP 72   // row pad (elems): 144 B = 16B-aligned for ds_read_b128
__global__ __launch_bounds__(256) void favor_mfma(
    const bf16* pq, const bf16* __restrict__ pk,
    const bf16* __restrict__ v, bf16* ao)
{
    const int bh = blockIdx.x;
    const int b = bh >> 3, h = bh & 7;
    const long base = ((long)b * 513 * 8 + h) * 64;   // elem (s,m) = base + s*512 + m

    __shared__ bf16 pkT[64][FP];
    __shared__ bf16 vT [64][FP];
    __shared__ bf16 kvT[64][FP];
    __shared__ bf16 pqS[64][FP];
    __shared__ float ksumS[64];
    __shared__ float denS[64];

    const int tid  = threadIdx.x;
    const int wave = tid >> 6;
    const int lane = tid & 63;
    const int q    = lane >> 4;
    const int lm   = lane & 15;
    const int wr   = wave >> 1, wc = wave & 1;
    const int mp   = (tid & 31) * 2;   // m pair for transposed staging
    const int sr   = tid >> 5;         // 0..7

    if (tid < 64) ksumS[tid] = 0.f;
    float ksp0 = 0.f, ksp1 = 0.f;

    f32x4 akv[2][2];
    for (int i = 0; i < 2; i++) for (int j = 0; j < 2; j++)
        for (int r = 0; r < 4; r++) akv[i][j][r] = 0.f;

    // ---------------- Phase A: kv + ksum ----------------
    for (int t8 = 0; t8 < 9; t8++) {
        const int s0 = t8 * 64;
        #pragma unroll
        for (int i = 0; i < 8; i++) {
            const int s  = sr + i * 8;
            const int gs = s0 + s;
            unsigned pkw = 0, vw = 0;
            if (gs < 513) {
                pkw = *(const unsigned*)(pk + base + (long)gs * 512 + mp);
                vw  = *(const unsigned*)(v  + base + (long)gs * 512 + mp);
            }
            union { unsigned u; bf16 hh[2]; } pu, vu;
            pu.u = pkw; vu.u = vw;
            pkT[mp][s]     = pu.hh[0];
            pkT[mp + 1][s] = pu.hh[1];
            vT[mp][s]      = vu.hh[0];
            vT[mp + 1][s]  = vu.hh[1];
            ksp0 += (float)pu.hh[0];
            ksp1 += (float)pu.hh[1];
        }
        __syncthreads();
        #pragma unroll
        for (int ks = 0; ks < 2; ks++) {
            bf16x8 a0 = *(const bf16x8*)(&pkT[wr * 32 + lm     ][ks * 32 + q * 8]);
            bf16x8 a1 = *(const bf16x8*)(&pkT[wr * 32 + 16 + lm][ks * 32 + q * 8]);
            bf16x8 b0 = *(const bf16x8*)(&vT [wc * 32 + lm     ][ks * 32 + q * 8]);
            bf16x8 b1 = *(const bf16x8*)(&vT [wc * 32 + 16 + lm][ks * 32 + q * 8]);
            akv[0][0] = __builtin_amdgcn_mfma_f32_16x16x32_bf16(a0, b0, akv[0][0], 0, 0, 0);
            akv[0][1] = __builtin_amdgcn_mfma_f32_16x16x32_bf16(a0, b1, akv[0][1], 0, 0, 0);
            akv[1][0] = __builtin_amdgcn_mfma_f32_16x16x32_bf16(a1, b0, akv[1][0], 0, 0, 0);
            akv[1][1] = __builtin_amdgcn_mfma_f32_16x16x32_bf16(a1, b1, akv[1][1], 0, 0, 0);
        }
        __syncthreads();
    }
    atomicAdd(&ksumS[mp],     ksp0);
    atomicAdd(&ksumS[mp + 1], ksp1);
    // kvT[d][m] from C/D layout: row=q*4+r -> m, col=lm -> d
    #pragma unroll
    for (int i = 0; i < 2; i++)
        #pragma unroll
        for (int j = 0; j < 2; j++)
            #pragma unroll
            for (int r = 0; r < 4; r++)
                kvT[wc * 32 + j * 16 + lm][wr * 32 + i * 16 + q * 4 + r] =
                    (bf16)akv[i][j][r];
    __syncthreads();

    // ---------------- Phase B: num/den + output ----------------
    const int prow = tid >> 2;
    const int pseg = (tid & 3) * 16;
    for (int t8 = 0; t8 < 9; t8++) {
        const int s0 = t8 * 64;
        const int gs = s0 + prow;
        if (gs < 513) {
            *(bf16x8*)(&pqS[prow][pseg])     = *(const bf16x8*)(pq + base + (long)gs * 512 + pseg);
            *(bf16x8*)(&pqS[prow][pseg + 8]) = *(const bf16x8*)(pq + base + (long)gs * 512 + pseg + 8);
        } else {
            bf16x8 z;
            for (int r = 0; r < 8; r++) z[r] = (bf16)0.f;
            *(bf16x8*)(&pqS[prow][pseg])     = z;
            *(bf16x8*)(&pqS[prow][pseg + 8]) = z;
        }
        __syncthreads();
        {   // den[s] = pq[s][:] . ksum  (4 threads per s)
            const int s = tid >> 2, mb = (tid & 3) * 16;
            float dp = 0.f;
            #pragma unroll
            for (int m2 = 0; m2 < 16; m2++)
                dp += (float)pqS[s][mb + m2] * ksumS[mb + m2];
            dp += __shfl_xor(dp, 1);
            dp += __shfl_xor(dp, 2);
            if ((tid & 3) == 0) denS[s] = dp;
        }
        __syncthreads();
        f32x4 an[4];
        for (int j = 0; j < 4; j++)
            for (int r = 0; r < 4; r++) an[j][r] = 0.f;
        #pragma unroll
        for (int ks = 0; ks < 2; ks++) {
            bf16x8 a = *(const bf16x8*)(&pqS[wave * 16 + lm][ks * 32 + q * 8]);
            #pragma unroll
            for (int j = 0; j < 4; j++) {
                bf16x8 bb = *(const bf16x8*)(&kvT[j * 16 + lm][ks * 32 + q * 8]);
                an[j] = __builtin_amdgcn_mfma_f32_16x16x32_bf16(a, bb, an[j], 0, 0, 0);
            }
        }
        #pragma unroll
        for (int j = 0; j < 4; j++) {
            #pragma unroll
            for (int r = 0; r < 4; r++) {
                const int sl  = wave * 16 + q * 4 + r;
                const int gs2 = s0 + sl;
                if (gs2 < 513) {
                    const int d = j * 16 + lm;
                    ao[base + (long)gs2 * 512 + d] = (bf16)(an[j][r] / denS[sl]);
                }
            }
        }
        __syncthreads();
    }
}

// xb = LN(y + xb) * s + b  (bf16 in/out, fp32 math/params). wave/row.
__global__ __launch_bounds__(256) void ln_res(
    const bf16* __restrict__ y, const float* __restrict__ sc,
    const float* __restrict__ bi, bf16* __restrict__ xb)
{
    const int row  = blockIdx.x * 4 + (threadIdx.x >> 6);
    const int lane = threadIdx.x & 63;
    const bf16* yr = y  + (long)row * 512 + lane * 8;
    bf16*       xr = xb + (long)row * 512 + lane * 8;
    bf16x8 yv = *(const bf16x8*)yr;
    bf16x8 xv = *(const bf16x8*)xr;
    float v[8];
    float sum = 0.f;
    #pragma unroll
    for (int i = 0; i < 8; i++) { v[i] = (float)yv[i] + (float)xv[i]; sum += v[i]; }
    #pragma unroll
    for (int o = 32; o; o >>= 1) sum += __shfl_xor(sum, o);
    const float mean = sum * (1.f / 512.f);
    float vs = 0.f;
    #pragma unroll
    for (int i = 0; i < 8; i++) { float dd = v[i] - mean; vs += dd * dd; }
    #pragma unroll
    for (int o = 32; o; o >>= 1) vs += __shfl_xor(vs, o);
    const float rstd = rsqrtf(vs * (1.f / 512.f) + 1e-6f);
    bf16x8 ov;
    #pragma unroll
    for (int i = 0; i < 8; i++)
        ov[i] = (bf16)((v[i] - mean) * rstd * sc[lane * 8 + i] + bi[lane * 8 + i]);
    *(bf16x8*)xr = ov;
}

// FP32 OUTPUT: out[0:32768] = x[:,0,:]; out[32768:] = x[:,0,:]@Wqp + bqp
__global__ __launch_bounds__(256) void final_head(
    const bf16* __restrict__ xb, const float* __restrict__ Wqp,
    const float* __restrict__ bqp, float* __restrict__ out)
{
    const int b = blockIdx.x;
    const bf16* xr = xb + (long)b * 513 * 512;
    for (int i = threadIdx.x; i < 512; i += 256) out[b * 512 + i] = (float)xr[i];
    const int a = threadIdx.x & 15, g = threadIdx.x >> 4;
    float p = 0.f;
    for (int k = g * 32; k < g * 32 + 32; k++)
        p += (float)xr[k] * Wqp[k * 16 + a];
    __shared__ float red[256];
    red[threadIdx.x] = p;
    __syncthreads();
    if (threadIdx.x < 16) {
        float s = bqp[a];
        for (int g2 = 0; g2 < 16; g2++) s += red[g2 * 16 + a];
        out[64 * 512 + b * 16 + a] = s;
    }
}

extern "C" void kernel_launch(void* const* d_in, const int* in_sizes, int n_in,
                              void* d_out, int out_size, void* d_ws, size_t ws_size,
                              hipStream_t stream)
{
    (void)in_sizes; (void)n_in; (void)out_size; (void)ws_size;
    const float* hs    = (const float*)d_in[0];
    const float* ins   = (const float*)d_in[1];
    const int*   resets= (const int*)d_in[2];
    const float* W_emb = (const float*)d_in[3];
    const float* b_emb = (const float*)d_in[4];
    const float* Wq    = (const float*)d_in[5];
    const float* bq    = (const float*)d_in[6];
    const float* Wk    = (const float*)d_in[7];
    const float* bk    = (const float*)d_in[8];
    const float* Wv    = (const float*)d_in[9];
    const float* bv    = (const float*)d_in[10];
    const float* Wo    = (const float*)d_in[11];
    const float* bo    = (const float*)d_in[12];
    const float* ln1s  = (const float*)d_in[13];
    const float* ln1b  = (const float*)d_in[14];
    const float* ln2s  = (const float*)d_in[15];
    const float* ln2b  = (const float*)d_in[16];
    const float* W1    = (const float*)d_in[17];
    const float* b1    = (const float*)d_in[18];
    const float* W2    = (const float*)d_in[19];
    const float* b2    = (const float*)d_in[20];
    const float* Wqp   = (const float*)d_in[21];
    const float* bqp   = (const float*)d_in[22];
    float* out = (float*)d_out;
    char* ws  = (char*)d_ws;

    // ---- workspace layout (bytes), peak ~149.4 MB ----
    bf16* xb = (bf16*)(ws);                         // 33,619,968
    bf16* f  = (bf16*)(ws + 33619968);              // 67,371,008 (16448 x 2048)
    bf16* pq = f;                                   // alias
    bf16* pk = (bf16*)(ws + 67239936);
    bf16* vv = (bf16*)(ws + 100990976);             // y aliases
    bf16* ao = pq;
    bf16* y  = vv;
    bf16* WembT = (bf16*)(ws + 134610944);          // 131,072
    char* LW    = ws + 134742016;                   // 6,291,456 (per-layer WT)
    bf16* insb  = (bf16*)(ws + 141033472);          // 8,388,608

    const bf16* WqT = (const bf16*)(LW + 0);
    const bf16* WkT = (const bf16*)(LW + 524288);
    const bf16* WvT = (const bf16*)(LW + 1048576);
    const bf16* WoT = (const bf16*)(LW + 1572864);
    const bf16* W1T = (const bf16*)(LW + 2097152);
    const bf16* W2T = (const bf16*)(LW + 4194304);

    cvt_bf16<<<4096, 256, 0, stream>>>(ins, insb, 4194304);
    transpose_f32<<<dim3(16, 4), 256, 0, stream>>>(W_emb, WembT, 128, 512, 0);
    build_x0<<<64, 256, 0, stream>>>(hs, resets, xb);
    gemm128<1, 0><<<dim3(4, 256), 256, 0, stream>>>(
        insb, WembT, b_emb, xb, 32768, 512, 128);

    for (int l = 0; l < 4; l++) {
        const long o512  = (long)l * 262144;
        const long o2048 = (long)l * 1048576;
        transpose_f32<<<dim3(16, 16), 256, 0, stream>>>(Wq, (bf16*)(LW + 0),       512, 512,  o512);
        transpose_f32<<<dim3(16, 16), 256, 0, stream>>>(Wk, (bf16*)(LW + 524288),  512, 512,  o512);
        transpose_f32<<<dim3(16, 16), 256, 0, stream>>>(Wv, (bf16*)(LW + 1048576), 512, 512,  o512);
        transpose_f32<<<dim3(16, 16), 256, 0, stream>>>(Wo, (bf16*)(LW + 1572864), 512, 512,  o512);
        transpose_f32<<<dim3(64, 16), 256, 0, stream>>>(W1, (bf16*)(LW + 2097152), 512, 2048, o2048);
        transpose_f32<<<dim3(16, 64), 256, 0, stream>>>(W2, (bf16*)(LW + 4194304), 2048, 512, o2048);

        gemm128<0, 2><<<dim3(4, 257), 256, 0, stream>>>(
            xb, WqT, bq + l * 512, pq, 32832, 512, 512);
        gemm128<0, 2><<<dim3(4, 257), 256, 0, stream>>>(
            xb, WkT, bk + l * 512, pk, 32832, 512, 512);
        gemm128<0, 0><<<dim3(4, 257), 256, 0, stream>>>(
            xb, WvT, bv + l * 512, vv, 32832, 512, 512);
        favor_mfma<<<512, 256, 0, stream>>>(pq, pk, vv, ao);
        gemm128<0, 0><<<dim3(4, 257), 256, 0, stream>>>(
            ao, WoT, bo + l * 512, y, 32832, 512, 512);
        ln_res<<<8208, 256, 0, stream>>>(y, ln1s + l * 512, ln1b + l * 512, xb);

        const int r0s[2] = {0, 16384};
        const int mcs[2] = {16384, 16448};
        for (int c = 0; c < 2; c++) {
            gemm128<0, 1><<<dim3(16, (mcs[c] + 127) / 128), 256, 0, stream>>>(
                xb + (long)r0s[c] * 512, W1T, b1 + l * 2048, f, mcs[c], 2048, 512);
            gemm128<0, 0><<<dim3(4, (mcs[c] + 127) / 128), 256, 0, stream>>>(
                f, W2T, b2 + l * 512, y + (long)r0s[c] * 512, mcs[c], 512, 2048);
        }
        ln_res<<<8208, 256, 0, stream>>>(y, ln2s + l * 512, ln2b + l * 512, xb);
    }

    final_head<<<64, 256, 0, stream>>>(xb, Wqp, bqp, out);
}

// Round 15
// 2040.273 us; speedup vs baseline: 1.6213x; 1.0478x over previous
//
#include <hip/hip_runtime.h>

typedef __bf16 bf16;
typedef __bf16 bf16x8 __attribute__((ext_vector_type(8)));
typedef float  f32x4  __attribute__((ext_vector_type(4)));

// B=64, S=512, OBS=128, D=512, H=8, F=2048, L=4, A=16; rows M = B*513 = 32832
// R15: gemm128 staging -> __builtin_amdgcn_global_load_lds width=16 (ladder
// m93->m97, the 1.69x step). LDS tiles UNPADDED [128][32] (DMA lane-order
// constraint). Everything else identical to the passing R14.

__device__ __forceinline__ void cp16(const bf16* g, bf16* l)
{
    __builtin_amdgcn_global_load_lds(
        (const __attribute__((address_space(1))) void*)g,
        (__attribute__((address_space(3))) void*)l,
        16, 0, 0);
}

__global__ __launch_bounds__(256) void cvt_bf16(
    const float* __restrict__ src, bf16* __restrict__ dst, int n)
{
    for (int i = blockIdx.x * 256 + threadIdx.x; i < n; i += gridDim.x * 256)
        dst[i] = (bf16)src[i];
}

__global__ __launch_bounds__(256) void transpose_f32(
    const float* __restrict__ W, bf16* __restrict__ WT, int K, int N, long elemOff)
{
    __shared__ bf16 tile[32][33];
    const int bn = blockIdx.x * 32;
    const int bk = blockIdx.y * 32;
    const int tx = threadIdx.x & 31, ty = threadIdx.x >> 5;
    for (int r = 0; r < 32; r += 8)
        tile[ty + r][tx] = (bf16)W[elemOff + (long)(bk + ty + r) * N + (bn + tx)];
    __syncthreads();
    for (int r = 0; r < 32; r += 8)
        WT[(long)(bn + ty + r) * K + (bk + tx)] = tile[tx][ty + r];
}

__global__ __launch_bounds__(256) void build_x0(
    const float* __restrict__ hs, const int* __restrict__ resets,
    bf16* __restrict__ xb)
{
    const int b = blockIdx.x;
    const bool rz = (resets[b] != 0);
    const long base = (long)b * 513 * 512;
    for (int d = threadIdx.x; d < 512; d += 256)
        xb[base + d] = rz ? (bf16)0.f : (bf16)hs[b * 512 + d];
}

// GEMM: C[M,N] = A[M,K] @ BT[N,K]^T + bias(fp32).  128x128 tile, BK=32,
// 4 waves x (4x4) 16x16x32 MFMA, global_load_lds(16B) direct-to-LDS staging.
// LDS layout UNPADDED [128][32]: wave w issue i deposits rows w*32+i*16+(l>>2),
// seg (l&3)*8 at lds elem base + l*8 -- exactly row*32 + seg*8.  N%128==0;
// M tail via overlap clamp. ROWMAP==1: row += row/512 + 1. ACT:0/1/2.
template<int ROWMAP, int ACT>
__global__ __launch_bounds__(256) void gemm128(
    const bf16* __restrict__ A, const bf16* __restrict__ BT,
    const float* __restrict__ bias, bf16* __restrict__ outB,
    int M, int N, int K)
{
    __shared__ bf16 As[128 * 32];
    __shared__ bf16 Bs[128 * 32];
    const int tid  = threadIdx.x;
    const int wave = tid >> 6;
    const int lane = tid & 63;
    const int q    = lane >> 4;
    const int lm   = lane & 15;
    const int wr   = wave >> 1, wc = wave & 1;
    int m0 = blockIdx.y * 128;
    if (m0 > M - 128) m0 = M - 128;            // tail overlap clamp
    const int n0 = blockIdx.x * 128;

    // async staging geometry (see header comment)
    const int r0 = wave * 32 + (lane >> 2);
    const int ks = (lane & 3) * 8;
    const bf16* Ag0 = A  + (long)(m0 + r0) * K + ks;
    const bf16* Ag1 = A  + (long)(m0 + r0 + 16) * K + ks;
    const bf16* Bg0 = BT + (long)(n0 + r0) * K + ks;
    const bf16* Bg1 = BT + (long)(n0 + r0 + 16) * K + ks;
    bf16* Al0 = As + wave * 1024;
    bf16* Al1 = As + wave * 1024 + 512;
    bf16* Bl0 = Bs + wave * 1024;
    bf16* Bl1 = Bs + wave * 1024 + 512;

    f32x4 acc[4][4];
    for (int i = 0; i < 4; i++) for (int j = 0; j < 4; j++)
        for (int r = 0; r < 4; r++) acc[i][j][r] = 0.f;

    for (int k0 = 0; k0 < K; k0 += 32) {
        cp16(Ag0 + k0, Al0);
        cp16(Ag1 + k0, Al1);
        cp16(Bg0 + k0, Bl0);
        cp16(Bg1 + k0, Bl1);
        __syncthreads();                       // drains vmcnt -> DMA landed
        bf16x8 af[4], bfr[4];
        #pragma unroll
        for (int i = 0; i < 4; i++)
            af[i] = *(const bf16x8*)(As + (wr * 64 + i * 16 + lm) * 32 + q * 8);
        #pragma unroll
        for (int j = 0; j < 4; j++)
            bfr[j] = *(const bf16x8*)(Bs + (wc * 64 + j * 16 + lm) * 32 + q * 8);
        #pragma unroll
        for (int i = 0; i < 4; i++)
            #pragma unroll
            for (int j = 0; j < 4; j++)
                acc[i][j] = __builtin_amdgcn_mfma_f32_16x16x32_bf16(
                    af[i], bfr[j], acc[i][j], 0, 0, 0);
        __syncthreads();                       // LDS safe for next DMA
    }

    // C/D: col = lane&15, row = (lane>>4)*4 + r  [session-verified]
    #pragma unroll
    for (int j = 0; j < 4; j++) {
        const int col = n0 + wc * 64 + j * 16 + lm;
        const float bv = bias[col];
        #pragma unroll
        for (int i = 0; i < 4; i++) {
            #pragma unroll
            for (int r = 0; r < 4; r++) {
                int row = m0 + wr * 64 + i * 16 + q * 4 + r;
                float vv = acc[i][j][r] + bv;
                if (ACT >= 1) vv = fmaxf(vv, 0.f);
                if (ACT == 2) vv += 1e-3f;
                if (ROWMAP == 1) row = row + (row >> 9) + 1;
                outB[(long)row * N + col] = (bf16)vv;
            }
        }
    }
}

// FAVOR+ attention, full MFMA (R14, numerically validated).
#define FP 72
__global__ __launch_bounds__(256) void favor_mfma(
    const bf16* pq, const bf16* __restrict__ pk,
    const bf16* __restrict__ v, bf16* ao)
{
    const int bh = blockIdx.x;
    const int b = bh >> 3, h = bh & 7;
    const long base = ((long)b * 513 * 8 + h) * 64;

    __shared__ bf16 pkT[64][FP];
    __shared__ bf16 vT [64][FP];
    __shared__ bf16 kvT[64][FP];
    __shared__ bf16 pqS[64][FP];
    __shared__ float ksumS[64];
    __shared__ float denS[64];

    const int tid  = threadIdx.x;
    const int wave = tid >> 6;
    const int lane = tid & 63;
    const int q    = lane >> 4;
    const int lm   = lane & 15;
    const int wr   = wave >> 1, wc = wave & 1;
    const int mp   = (tid & 31) * 2;
    const int sr   = tid >> 5;

    if (tid < 64) ksumS[tid] = 0.f;
    float ksp0 = 0.f, ksp1 = 0.f;

    f32x4 akv[2][2];
    for (int i = 0; i < 2; i++) for (int j = 0; j < 2; j++)
        for (int r = 0; r < 4; r++) akv[i][j][r] = 0.f;

    for (int t8 = 0; t8 < 9; t8++) {
        const int s0 = t8 * 64;
        #pragma unroll
        for (int i = 0; i < 8; i++) {
            const int s  = sr + i * 8;
            const int gs = s0 + s;
            unsigned pkw = 0, vw = 0;
            if (gs < 513) {
                pkw = *(const unsigned*)(pk + base + (long)gs * 512 + mp);
                vw  = *(const unsigned*)(v  + base + (long)gs * 512 + mp);
            }
            union { unsigned u; bf16 hh[2]; } pu, vu;
            pu.u = pkw; vu.u = vw;
            pkT[mp][s]     = pu.hh[0];
            pkT[mp + 1][s] = pu.hh[1];
            vT[mp][s]      = vu.hh[0];
            vT[mp + 1][s]  = vu.hh[1];
            ksp0 += (float)pu.hh[0];
            ksp1 += (float)pu.hh[1];
        }
        __syncthreads();
        #pragma unroll
        for (int ks = 0; ks < 2; ks++) {
            bf16x8 a0 = *(const bf16x8*)(&pkT[wr * 32 + lm     ][ks * 32 + q * 8]);
            bf16x8 a1 = *(const bf16x8*)(&pkT[wr * 32 + 16 + lm][ks * 32 + q * 8]);
            bf16x8 b0 = *(const bf16x8*)(&vT [wc * 32 + lm     ][ks * 32 + q * 8]);
            bf16x8 b1 = *(const bf16x8*)(&vT [wc * 32 + 16 + lm][ks * 32 + q * 8]);
            akv[0][0] = __builtin_amdgcn_mfma_f32_16x16x32_bf16(a0, b0, akv[0][0], 0, 0, 0);
            akv[0][1] = __builtin_amdgcn_mfma_f32_16x16x32_bf16(a0, b1, akv[0][1], 0, 0, 0);
            akv[1][0] = __builtin_amdgcn_mfma_f32_16x16x32_bf16(a1, b0, akv[1][0], 0, 0, 0);
            akv[1][1] = __builtin_amdgcn_mfma_f32_16x16x32_bf16(a1, b1, akv[1][1], 0, 0, 0);
        }
        __syncthreads();
    }
    atomicAdd(&ksumS[mp],     ksp0);
    atomicAdd(&ksumS[mp + 1], ksp1);
    #pragma unroll
    for (int i = 0; i < 2; i++)
        #pragma unroll
        for (int j = 0; j < 2; j++)
            #pragma unroll
            for (int r = 0; r < 4; r++)
                kvT[wc * 32 + j * 16 + lm][wr * 32 + i * 16 + q * 4 + r] =
                    (bf16)akv[i][j][r];
    __syncthreads();

    const int prow = tid >> 2;
    const int pseg = (tid & 3) * 16;
    for (int t8 = 0; t8 < 9; t8++) {
        const int s0 = t8 * 64;
        const int gs = s0 + prow;
        if (gs < 513) {
            *(bf16x8*)(&pqS[prow][pseg])     = *(const bf16x8*)(pq + base + (long)gs * 512 + pseg);
            *(bf16x8*)(&pqS[prow][pseg + 8]) = *(const bf16x8*)(pq + base + (long)gs * 512 + pseg + 8);
        } else {
            bf16x8 z;
            for (int r = 0; r < 8; r++) z[r] = (bf16)0.f;
            *(bf16x8*)(&pqS[prow][pseg])     = z;
            *(bf16x8*)(&pqS[prow][pseg + 8]) = z;
        }
        __syncthreads();
        {
            const int s = tid >> 2, mb = (tid & 3) * 16;
            float dp = 0.f;
            #pragma unroll
            for (int m2 = 0; m2 < 16; m2++)
                dp += (float)pqS[s][mb + m2] * ksumS[mb + m2];
            dp += __shfl_xor(dp, 1);
            dp += __shfl_xor(dp, 2);
            if ((tid & 3) == 0) denS[s] = dp;
        }
        __syncthreads();
        f32x4 an[4];
        for (int j = 0; j < 4; j++)
            for (int r = 0; r < 4; r++) an[j][r] = 0.f;
        #pragma unroll
        for (int ks = 0; ks < 2; ks++) {
            bf16x8 a = *(const bf16x8*)(&pqS[wave * 16 + lm][ks * 32 + q * 8]);
            #pragma unroll
            for (int j = 0; j < 4; j++) {
                bf16x8 bb = *(const bf16x8*)(&kvT[j * 16 + lm][ks * 32 + q * 8]);
                an[j] = __builtin_amdgcn_mfma_f32_16x16x32_bf16(a, bb, an[j], 0, 0, 0);
            }
        }
        #pragma unroll
        for (int j = 0; j < 4; j++) {
            #pragma unroll
            for (int r = 0; r < 4; r++) {
                const int sl  = wave * 16 + q * 4 + r;
                const int gs2 = s0 + sl;
                if (gs2 < 513) {
                    const int d = j * 16 + lm;
                    ao[base + (long)gs2 * 512 + d] = (bf16)(an[j][r] / denS[sl]);
                }
            }
        }
        __syncthreads();
    }
}

__global__ __launch_bounds__(256) void ln_res(
    const bf16* __restrict__ y, const float* __restrict__ sc,
    const float* __restrict__ bi, bf16* __restrict__ xb)
{
    const int row  = blockIdx.x * 4 + (threadIdx.x >> 6);
    const int lane = threadIdx.x & 63;
    const bf16* yr = y  + (long)row * 512 + lane * 8;
    bf16*       xr = xb + (long)row * 512 + lane * 8;
    bf16x8 yv = *(const bf16x8*)yr;
    bf16x8 xv = *(const bf16x8*)xr;
    float v[8];
    float sum = 0.f;
    #pragma unroll
    for (int i = 0; i < 8; i++) { v[i] = (float)yv[i] + (float)xv[i]; sum += v[i]; }
    #pragma unroll
    for (int o = 32; o; o >>= 1) sum += __shfl_xor(sum, o);
    const float mean = sum * (1.f / 512.f);
    float vs = 0.f;
    #pragma unroll
    for (int i = 0; i < 8; i++) { float dd = v[i] - mean; vs += dd * dd; }
    #pragma unroll
    for (int o = 32; o; o >>= 1) vs += __shfl_xor(vs, o);
    const float rstd = rsqrtf(vs * (1.f / 512.f) + 1e-6f);
    bf16x8 ov;
    #pragma unroll
    for (int i = 0; i < 8; i++)
        ov[i] = (bf16)((v[i] - mean) * rstd * sc[lane * 8 + i] + bi[lane * 8 + i]);
    *(bf16x8*)xr = ov;
}

__global__ __launch_bounds__(256) void final_head(
    const bf16* __restrict__ xb, const float* __restrict__ Wqp,
    const float* __restrict__ bqp, float* __restrict__ out)
{
    const int b = blockIdx.x;
    const bf16* xr = xb + (long)b * 513 * 512;
    for (int i = threadIdx.x; i < 512; i += 256) out[b * 512 + i] = (float)xr[i];
    const int a = threadIdx.x & 15, g = threadIdx.x >> 4;
    float p = 0.f;
    for (int k = g * 32; k < g * 32 + 32; k++)
        p += (float)xr[k] * Wqp[k * 16 + a];
    __shared__ float red[256];
    red[threadIdx.x] = p;
    __syncthreads();
    if (threadIdx.x < 16) {
        float s = bqp[a];
        for (int g2 = 0; g2 < 16; g2++) s += red[g2 * 16 + a];
        out[64 * 512 + b * 16 + a] = s;
    }
}

extern "C" void kernel_launch(void* const* d_in, const int* in_sizes, int n_in,
                              void* d_out, int out_size, void* d_ws, size_t ws_size,
                              hipStream_t stream)
{
    (void)in_sizes; (void)n_in; (void)out_size; (void)ws_size;
    const float* hs    = (const float*)d_in[0];
    const float* ins   = (const float*)d_in[1];
    const int*   resets= (const int*)d_in[2];
    const float* W_emb = (const float*)d_in[3];
    const float* b_emb = (const float*)d_in[4];
    const float* Wq    = (const float*)d_in[5];
    const float* bq    = (const float*)d_in[6];
    const float* Wk    = (const float*)d_in[7];
    const float* bk    = (const float*)d_in[8];
    const float* Wv    = (const float*)d_in[9];
    const float* bv    = (const float*)d_in[10];
    const float* Wo    = (const float*)d_in[11];
    const float* bo    = (const float*)d_in[12];
    const float* ln1s  = (const float*)d_in[13];
    const float* ln1b  = (const float*)d_in[14];
    const float* ln2s  = (const float*)d_in[15];
    const float* ln2b  = (const float*)d_in[16];
    const float* W1    = (const float*)d_in[17];
    const float* b1    = (const float*)d_in[18];
    const float* W2    = (const float*)d_in[19];
    const float* b2    = (const float*)d_in[20];
    const float* Wqp   = (const float*)d_in[21];
    const float* bqp   = (const float*)d_in[22];
    float* out = (float*)d_out;
    char* ws  = (char*)d_ws;

    // ---- workspace layout (bytes), peak ~149.4 MB ----
    bf16* xb = (bf16*)(ws);
    bf16* f  = (bf16*)(ws + 33619968);
    bf16* pq = f;
    bf16* pk = (bf16*)(ws + 67239936);
    bf16* vv = (bf16*)(ws + 100990976);
    bf16* ao = pq;
    bf16* y  = vv;
    bf16* WembT = (bf16*)(ws + 134610944);
    char* LW    = ws + 134742016;
    bf16* insb  = (bf16*)(ws + 141033472);

    const bf16* WqT = (const bf16*)(LW + 0);
    const bf16* WkT = (const bf16*)(LW + 524288);
    const bf16* WvT = (const bf16*)(LW + 1048576);
    const bf16* WoT = (const bf16*)(LW + 1572864);
    const bf16* W1T = (const bf16*)(LW + 2097152);
    const bf16* W2T = (const bf16*)(LW + 4194304);

    cvt_bf16<<<4096, 256, 0, stream>>>(ins, insb, 4194304);
    transpose_f32<<<dim3(16, 4), 256, 0, stream>>>(W_emb, WembT, 128, 512, 0);
    build_x0<<<64, 256, 0, stream>>>(hs, resets, xb);
    gemm128<1, 0><<<dim3(4, 256), 256, 0, stream>>>(
        insb, WembT, b_emb, xb, 32768, 512, 128);

    for (int l = 0; l < 4; l++) {
        const long o512  = (long)l * 262144;
        const long o2048 = (long)l * 1048576;
        transpose_f32<<<dim3(16, 16), 256, 0, stream>>>(Wq, (bf16*)(LW + 0),       512, 512,  o512);
        transpose_f32<<<dim3(16, 16), 256, 0, stream>>>(Wk, (bf16*)(LW + 524288),  512, 512,  o512);
        transpose_f32<<<dim3(16, 16), 256, 0, stream>>>(Wv, (bf16*)(LW + 1048576), 512, 512,  o512);
        transpose_f32<<<dim3(16, 16), 256, 0, stream>>>(Wo, (bf16*)(LW + 1572864), 512, 512,  o512);
        transpose_f32<<<dim3(64, 16), 256, 0, stream>>>(W1, (bf16*)(LW + 2097152), 512, 2048, o2048);
        transpose_f32<<<dim3(16, 64), 256, 0, stream>>>(W2, (bf16*)(LW + 4194304), 2048, 512, o2048);

        gemm128<0, 2><<<dim3(4, 257), 256, 0, stream>>>(
            xb, WqT, bq + l * 512, pq, 32832, 512, 512);
        gemm128<0, 2><<<dim3(4, 257), 256, 0, stream>>>(
            xb, WkT, bk + l * 512, pk, 32832, 512, 512);
        gemm128<0, 0><<<dim3(4, 257), 256, 0, stream>>>(
            xb, WvT, bv + l * 512, vv, 32832, 512, 512);
        favor_mfma<<<512, 256, 0, stream>>>(pq, pk, vv, ao);
        gemm128<0, 0><<<dim3(4, 257), 256, 0, stream>>>(
            ao, WoT, bo + l * 512, y, 32832, 512, 512);
        ln_res<<<8208, 256, 0, stream>>>(y, ln1s + l * 512, ln1b + l * 512, xb);

        const int r0s[2] = {0, 16384};
        const int mcs[2] = {16384, 16448};
        for (int c = 0; c < 2; c++) {
            gemm128<0, 1><<<dim3(16, (mcs[c] + 127) / 128), 256, 0, stream>>>(
                xb + (long)r0s[c] * 512, W1T, b1 + l * 2048, f, mcs[c], 2048, 512);
            gemm128<0, 0><<<dim3(4, (mcs[c] + 127) / 128), 256, 0, stream>>>(
                f, W2T, b2 + l * 512, y + (long)r0s[c] * 512, mcs[c], 512, 2048);
        }
        ln_res<<<8208, 256, 0, stream>>>(y, ln2s + l * 512, ln2b + l * 512, xb);
    }

    final_head<<<64, 256, 0, stream>>>(xb, Wqp, bqp, out);
}